// Round 1
// baseline (2259.882 us; speedup 1.0000x reference)
//
#include <hip/hip_runtime.h>

// SparseMatrixEquivariantLayer on MI355X.
// Decomposition:
//   memset ws accumulators
//   kA: per-(entry,feature) atomics -> sum_row, sum_col, Dsum, cnt_row, cnt_col; block partials for pa
//   kN: per-node matvecs -> row_b, col_b, diag_b; block partials for pd
//   kS: reduce partials, compute const_all = all_scalar+bias0, const_diag = diag_scalar+bias1
//   kB: per-entry Y = vals@W0 + row_b[r] + col_b[c] + const_all + dm*(diag_b[r]+const_diag)
//   kC: transpose scatter: Y[tout] += vals[tin]@W1 (atomic)

#define NNODES 100000
#define DF 16
#define NBLKA 2048

__global__ __launch_bounds__(256) void kA(
    const float* __restrict__ vals, const int* __restrict__ row,
    const int* __restrict__ col, int nnz,
    float* __restrict__ sum_row, float* __restrict__ sum_col,
    float* __restrict__ Dsum, float* __restrict__ cnt_row,
    float* __restrict__ cnt_col, float* __restrict__ pa_part)
{
    const long long total = (long long)nnz * DF;
    const int f = threadIdx.x & 15;
    const long long stride = (long long)gridDim.x * blockDim.x;  // multiple of 16
    float pa = 0.f;
    for (long long pos = (long long)blockIdx.x * blockDim.x + threadIdx.x;
         pos < total; pos += stride) {
        int e = (int)(pos >> 4);
        float v = vals[pos];
        int r = row[e];
        int c = col[e];
        pa += v;
        atomicAdd(&sum_row[(size_t)r * DF + f], v);
        atomicAdd(&sum_col[(size_t)c * DF + f], v);
        if (r == c) atomicAdd(&Dsum[(size_t)r * DF + f], v);
        if (f == 0) {
            atomicAdd(&cnt_row[r], 1.f);
            atomicAdd(&cnt_col[c], 1.f);
        }
    }
    __shared__ float red[256];
    red[threadIdx.x] = pa;
    __syncthreads();
    if (threadIdx.x < 16) {
        float s = 0.f;
        for (int k = threadIdx.x; k < 256; k += 16) s += red[k];
        pa_part[blockIdx.x * DF + threadIdx.x] = s;
    }
}

__global__ __launch_bounds__(256) void kN(
    const float* __restrict__ W,
    const float* __restrict__ sum_row, const float* __restrict__ sum_col,
    const float* __restrict__ Dsum, const float* __restrict__ cnt_row,
    const float* __restrict__ cnt_col,
    float* __restrict__ row_b, float* __restrict__ col_b,
    float* __restrict__ diag_b, float* __restrict__ pd_part, int n)
{
    // stage W2..W10 (9 x 16x16) into LDS; sw[(k-2)*256 + i*16 + j]
    __shared__ float sw[9 * 256];
    __shared__ float spd[16];
    for (int i = threadIdx.x; i < 9 * 256; i += blockDim.x) sw[i] = W[2 * 256 + i];
    if (threadIdx.x < 16) spd[threadIdx.x] = 0.f;
    __syncthreads();

    int node = blockIdx.x * blockDim.x + threadIdx.x;
    float D[16];
    if (node < n) {
        float Pr[16], Pc[16];
        float cr = fmaxf(cnt_row[node], 1.f);
        float cc = fmaxf(cnt_col[node], 1.f);
        float icr = 1.f / cr, icc = 1.f / cc;
        #pragma unroll
        for (int i = 0; i < 16; ++i) {
            D[i]  = Dsum[(size_t)node * DF + i];
            Pr[i] = sum_row[(size_t)node * DF + i] * icr;
            Pc[i] = sum_col[(size_t)node * DF + i] * icc;
        }
        #pragma unroll
        for (int j = 0; j < 16; ++j) {
            float db = 0.f, rb = 0.f, cb = 0.f;
            #pragma unroll
            for (int i = 0; i < 16; ++i) {
                float Di = D[i], Pri = Pr[i], Pci = Pc[i];
                db = fmaf(Di,  sw[0 * 256 + i * 16 + j], db);  // W2
                rb = fmaf(Di,  sw[1 * 256 + i * 16 + j], rb);  // W3
                cb = fmaf(Di,  sw[2 * 256 + i * 16 + j], cb);  // W4
                db = fmaf(Pri, sw[3 * 256 + i * 16 + j], db);  // W5
                rb = fmaf(Pri, sw[4 * 256 + i * 16 + j], rb);  // W6
                cb = fmaf(Pri, sw[5 * 256 + i * 16 + j], cb);  // W7
                db = fmaf(Pci, sw[6 * 256 + i * 16 + j], db);  // W8
                rb = fmaf(Pci, sw[7 * 256 + i * 16 + j], rb);  // W9
                cb = fmaf(Pci, sw[8 * 256 + i * 16 + j], cb);  // W10
            }
            diag_b[(size_t)node * DF + j] = db;
            row_b[(size_t)node * DF + j]  = rb;
            col_b[(size_t)node * DF + j]  = cb;
        }
        #pragma unroll
        for (int i = 0; i < 16; ++i) atomicAdd(&spd[i], D[i]);
    }
    __syncthreads();
    if (threadIdx.x < 16) pd_part[blockIdx.x * DF + threadIdx.x] = spd[threadIdx.x];
}

__global__ __launch_bounds__(256) void kS(
    const float* __restrict__ W, const float* __restrict__ bias,
    const float* __restrict__ pa_part, int nblka,
    const float* __restrict__ pd_part, int nblkn,
    float inv_nnz, float inv_n, float* __restrict__ cst)
{
    __shared__ float red[256];
    __shared__ float pa[16], pd[16];
    int t = threadIdx.x;
    int f = t & 15, g = t >> 4;
    float s = 0.f;
    for (int b = g; b < nblka; b += 16) s += pa_part[b * DF + f];
    red[t] = s;
    __syncthreads();
    if (t < 16) {
        float a = 0.f;
        for (int k = t; k < 256; k += 16) a += red[k];
        pa[t] = a * inv_nnz;
    }
    __syncthreads();
    s = 0.f;
    for (int b = g; b < nblkn; b += 16) s += pd_part[b * DF + f];
    red[t] = s;
    __syncthreads();
    if (t < 16) {
        float a = 0.f;
        for (int k = t; k < 256; k += 16) a += red[k];
        pd[t] = a * inv_n;
    }
    __syncthreads();
    if (t < 16) {
        float ds = 0.f, as = 0.f;
        #pragma unroll
        for (int i = 0; i < 16; ++i) {
            float pdi = pd[i], pai = pa[i];
            ds = fmaf(pdi, W[11 * 256 + i * 16 + t], ds);
            ds = fmaf(pai, W[13 * 256 + i * 16 + t], ds);
            as = fmaf(pdi, W[12 * 256 + i * 16 + t], as);
            as = fmaf(pai, W[14 * 256 + i * 16 + t], as);
        }
        cst[t]      = as + bias[t];       // const_all = all_scalar + bias0
        cst[16 + t] = ds + bias[16 + t];  // const_diag = diag_scalar + bias1
    }
}

__global__ __launch_bounds__(256) void kB(
    const float* __restrict__ vals, const int* __restrict__ row,
    const int* __restrict__ col, const float* __restrict__ W,
    const float* __restrict__ row_b, const float* __restrict__ col_b,
    const float* __restrict__ diag_b, const float* __restrict__ cst,
    float* __restrict__ out, int nnz)
{
    __shared__ float w0[256];
    __shared__ float scst[32];
    w0[threadIdx.x] = W[threadIdx.x];
    if (threadIdx.x < 32) scst[threadIdx.x] = cst[threadIdx.x];
    __syncthreads();

    int e = blockIdx.x * blockDim.x + threadIdx.x;
    if (e >= nnz) return;

    const float4* vp = (const float4*)(vals + (size_t)e * DF);
    float4 q0 = vp[0], q1 = vp[1], q2 = vp[2], q3 = vp[3];
    float v[16] = {q0.x, q0.y, q0.z, q0.w, q1.x, q1.y, q1.z, q1.w,
                   q2.x, q2.y, q2.z, q2.w, q3.x, q3.y, q3.z, q3.w};
    int r = row[e], c = col[e];

    float acc[16];
    const float4* rb = (const float4*)(row_b + (size_t)r * DF);
    const float4* cb = (const float4*)(col_b + (size_t)c * DF);
    #pragma unroll
    for (int k = 0; k < 4; ++k) {
        float4 a = rb[k], b = cb[k];
        acc[4 * k + 0] = scst[4 * k + 0] + a.x + b.x;
        acc[4 * k + 1] = scst[4 * k + 1] + a.y + b.y;
        acc[4 * k + 2] = scst[4 * k + 2] + a.z + b.z;
        acc[4 * k + 3] = scst[4 * k + 3] + a.w + b.w;
    }
    if (r == c) {
        const float4* db = (const float4*)(diag_b + (size_t)r * DF);
        #pragma unroll
        for (int k = 0; k < 4; ++k) {
            float4 d = db[k];
            acc[4 * k + 0] += d.x + scst[16 + 4 * k + 0];
            acc[4 * k + 1] += d.y + scst[16 + 4 * k + 1];
            acc[4 * k + 2] += d.z + scst[16 + 4 * k + 2];
            acc[4 * k + 3] += d.w + scst[16 + 4 * k + 3];
        }
    }
    #pragma unroll
    for (int i = 0; i < 16; ++i) {
        float vi = v[i];
        #pragma unroll
        for (int j = 0; j < 16; ++j) acc[j] = fmaf(vi, w0[i * 16 + j], acc[j]);
    }
    float4* op = (float4*)(out + (size_t)e * DF);
    op[0] = make_float4(acc[0], acc[1], acc[2], acc[3]);
    op[1] = make_float4(acc[4], acc[5], acc[6], acc[7]);
    op[2] = make_float4(acc[8], acc[9], acc[10], acc[11]);
    op[3] = make_float4(acc[12], acc[13], acc[14], acc[15]);
}

__global__ __launch_bounds__(256) void kC(
    const float* __restrict__ vals, const int* __restrict__ tin,
    const int* __restrict__ tout, const float* __restrict__ W,
    float* __restrict__ out, int nnzt)
{
    __shared__ float w1[256];
    w1[threadIdx.x] = W[256 + threadIdx.x];
    __syncthreads();

    int t = blockIdx.x * blockDim.x + threadIdx.x;
    if (t >= nnzt) return;
    int ei = tin[t], eo = tout[t];

    const float4* vp = (const float4*)(vals + (size_t)ei * DF);
    float4 q0 = vp[0], q1 = vp[1], q2 = vp[2], q3 = vp[3];
    float v[16] = {q0.x, q0.y, q0.z, q0.w, q1.x, q1.y, q1.z, q1.w,
                   q2.x, q2.y, q2.z, q2.w, q3.x, q3.y, q3.z, q3.w};
    float acc[16];
    #pragma unroll
    for (int j = 0; j < 16; ++j) acc[j] = 0.f;
    #pragma unroll
    for (int i = 0; i < 16; ++i) {
        float vi = v[i];
        #pragma unroll
        for (int j = 0; j < 16; ++j) acc[j] = fmaf(vi, w1[i * 16 + j], acc[j]);
    }
    float* op = out + (size_t)eo * DF;
    #pragma unroll
    for (int j = 0; j < 16; ++j) atomicAdd(&op[j], acc[j]);
}

extern "C" void kernel_launch(void* const* d_in, const int* in_sizes, int n_in,
                              void* d_out, int out_size, void* d_ws, size_t ws_size,
                              hipStream_t stream)
{
    const float* vals    = (const float*)d_in[0];
    const float* weights = (const float*)d_in[1];
    const float* bias    = (const float*)d_in[2];
    const int*   row     = (const int*)d_in[3];
    const int*   col     = (const int*)d_in[4];
    const int*   tin     = (const int*)d_in[5];
    const int*   tout    = (const int*)d_in[6];

    const int nnz  = in_sizes[0] / DF;
    const int nnzt = in_sizes[5];
    const int n    = NNODES;
    const int nblkn = (n + 255) / 256;

    float* ws = (float*)d_ws;
    float* sum_row = ws;
    float* sum_col = sum_row + (size_t)n * DF;
    float* Dsum    = sum_col + (size_t)n * DF;
    float* cnt_row = Dsum + (size_t)n * DF;
    float* cnt_col = cnt_row + n;
    float* row_b   = cnt_col + n;
    float* col_b   = row_b + (size_t)n * DF;
    float* diag_b  = col_b + (size_t)n * DF;
    float* pa_part = diag_b + (size_t)n * DF;
    float* pd_part = pa_part + (size_t)NBLKA * DF;
    float* cst     = pd_part + (size_t)nblkn * DF;

    // zero the atomic-accumulation region: sum_row..cnt_col == n*50 floats
    hipMemsetAsync(ws, 0, (size_t)n * 50 * sizeof(float), stream);

    kA<<<NBLKA, 256, 0, stream>>>(vals, row, col, nnz, sum_row, sum_col, Dsum,
                                  cnt_row, cnt_col, pa_part);
    kN<<<nblkn, 256, 0, stream>>>(weights, sum_row, sum_col, Dsum, cnt_row,
                                  cnt_col, row_b, col_b, diag_b, pd_part, n);
    kS<<<1, 256, 0, stream>>>(weights, bias, pa_part, NBLKA, pd_part, nblkn,
                              1.f / (float)nnz, 1.f / (float)n, cst);
    kB<<<(nnz + 255) / 256, 256, 0, stream>>>(vals, row, col, weights, row_b,
                                              col_b, diag_b, cst, (float*)d_out, nnz);
    kC<<<(nnzt + 255) / 256, 256, 0, stream>>>(vals, tin, tout, weights,
                                               (float*)d_out, nnzt);
}

// Round 2
// 1535.926 us; speedup vs baseline: 1.4713x; 1.4713x over previous
//
#include <hip/hip_runtime.h>

// SparseMatrixEquivariantLayer on MI355X.
// Decomposition:
//   memset ws accumulators
//   kA: per-(entry,feature) atomics -> sum_row, sum_col, Dsum, cnt_row, cnt_col; block partials for pa
//   kN: per-node matvecs -> row_b, col_b, diag_b; block partials for pd
//   kS: reduce partials, compute const_all = all_scalar+bias0, const_diag = diag_scalar+bias1
//   kB: per-entry Y = vals@W0 + row_b[r] + col_b[c] + const_all + dm*(diag_b[r]+const_diag)
//   kC: transpose scatter: Y[tout] += vals[tin]@W1, 16 lanes/entry so the 16
//       atomics land in ONE instruction on ONE 64B line (kA-style coalescing).

#define NNODES 100000
#define DF 16
#define NBLKA 2048

__global__ __launch_bounds__(256) void kA(
    const float* __restrict__ vals, const int* __restrict__ row,
    const int* __restrict__ col, int nnz,
    float* __restrict__ sum_row, float* __restrict__ sum_col,
    float* __restrict__ Dsum, float* __restrict__ cnt_row,
    float* __restrict__ cnt_col, float* __restrict__ pa_part)
{
    const long long total = (long long)nnz * DF;
    const int f = threadIdx.x & 15;
    const long long stride = (long long)gridDim.x * blockDim.x;  // multiple of 16
    float pa = 0.f;
    for (long long pos = (long long)blockIdx.x * blockDim.x + threadIdx.x;
         pos < total; pos += stride) {
        int e = (int)(pos >> 4);
        float v = vals[pos];
        int r = row[e];
        int c = col[e];
        pa += v;
        atomicAdd(&sum_row[(size_t)r * DF + f], v);
        atomicAdd(&sum_col[(size_t)c * DF + f], v);
        if (r == c) atomicAdd(&Dsum[(size_t)r * DF + f], v);
        if (f == 0) {
            atomicAdd(&cnt_row[r], 1.f);
            atomicAdd(&cnt_col[c], 1.f);
        }
    }
    __shared__ float red[256];
    red[threadIdx.x] = pa;
    __syncthreads();
    if (threadIdx.x < 16) {
        float s = 0.f;
        for (int k = threadIdx.x; k < 256; k += 16) s += red[k];
        pa_part[blockIdx.x * DF + threadIdx.x] = s;
    }
}

__global__ __launch_bounds__(256) void kN(
    const float* __restrict__ W,
    const float* __restrict__ sum_row, const float* __restrict__ sum_col,
    const float* __restrict__ Dsum, const float* __restrict__ cnt_row,
    const float* __restrict__ cnt_col,
    float* __restrict__ row_b, float* __restrict__ col_b,
    float* __restrict__ diag_b, float* __restrict__ pd_part, int n)
{
    // stage W2..W10 (9 x 16x16) into LDS; sw[(k-2)*256 + i*16 + j]
    __shared__ float sw[9 * 256];
    __shared__ float spd[16];
    for (int i = threadIdx.x; i < 9 * 256; i += blockDim.x) sw[i] = W[2 * 256 + i];
    if (threadIdx.x < 16) spd[threadIdx.x] = 0.f;
    __syncthreads();

    int node = blockIdx.x * blockDim.x + threadIdx.x;
    float D[16];
    if (node < n) {
        float Pr[16], Pc[16];
        float cr = fmaxf(cnt_row[node], 1.f);
        float cc = fmaxf(cnt_col[node], 1.f);
        float icr = 1.f / cr, icc = 1.f / cc;
        #pragma unroll
        for (int i = 0; i < 16; ++i) {
            D[i]  = Dsum[(size_t)node * DF + i];
            Pr[i] = sum_row[(size_t)node * DF + i] * icr;
            Pc[i] = sum_col[(size_t)node * DF + i] * icc;
        }
        #pragma unroll
        for (int j = 0; j < 16; ++j) {
            float db = 0.f, rb = 0.f, cb = 0.f;
            #pragma unroll
            for (int i = 0; i < 16; ++i) {
                float Di = D[i], Pri = Pr[i], Pci = Pc[i];
                db = fmaf(Di,  sw[0 * 256 + i * 16 + j], db);  // W2
                rb = fmaf(Di,  sw[1 * 256 + i * 16 + j], rb);  // W3
                cb = fmaf(Di,  sw[2 * 256 + i * 16 + j], cb);  // W4
                db = fmaf(Pri, sw[3 * 256 + i * 16 + j], db);  // W5
                rb = fmaf(Pri, sw[4 * 256 + i * 16 + j], rb);  // W6
                cb = fmaf(Pri, sw[5 * 256 + i * 16 + j], cb);  // W7
                db = fmaf(Pci, sw[6 * 256 + i * 16 + j], db);  // W8
                rb = fmaf(Pci, sw[7 * 256 + i * 16 + j], rb);  // W9
                cb = fmaf(Pci, sw[8 * 256 + i * 16 + j], cb);  // W10
            }
            diag_b[(size_t)node * DF + j] = db;
            row_b[(size_t)node * DF + j]  = rb;
            col_b[(size_t)node * DF + j]  = cb;
        }
        #pragma unroll
        for (int i = 0; i < 16; ++i) atomicAdd(&spd[i], D[i]);
    }
    __syncthreads();
    if (threadIdx.x < 16) pd_part[blockIdx.x * DF + threadIdx.x] = spd[threadIdx.x];
}

__global__ __launch_bounds__(256) void kS(
    const float* __restrict__ W, const float* __restrict__ bias,
    const float* __restrict__ pa_part, int nblka,
    const float* __restrict__ pd_part, int nblkn,
    float inv_nnz, float inv_n, float* __restrict__ cst)
{
    __shared__ float red[256];
    __shared__ float pa[16], pd[16];
    int t = threadIdx.x;
    int f = t & 15, g = t >> 4;
    float s = 0.f;
    for (int b = g; b < nblka; b += 16) s += pa_part[b * DF + f];
    red[t] = s;
    __syncthreads();
    if (t < 16) {
        float a = 0.f;
        for (int k = t; k < 256; k += 16) a += red[k];
        pa[t] = a * inv_nnz;
    }
    __syncthreads();
    s = 0.f;
    for (int b = g; b < nblkn; b += 16) s += pd_part[b * DF + f];
    red[t] = s;
    __syncthreads();
    if (t < 16) {
        float a = 0.f;
        for (int k = t; k < 256; k += 16) a += red[k];
        pd[t] = a * inv_n;
    }
    __syncthreads();
    if (t < 16) {
        float ds = 0.f, as = 0.f;
        #pragma unroll
        for (int i = 0; i < 16; ++i) {
            float pdi = pd[i], pai = pa[i];
            ds = fmaf(pdi, W[11 * 256 + i * 16 + t], ds);
            ds = fmaf(pai, W[13 * 256 + i * 16 + t], ds);
            as = fmaf(pdi, W[12 * 256 + i * 16 + t], as);
            as = fmaf(pai, W[14 * 256 + i * 16 + t], as);
        }
        cst[t]      = as + bias[t];       // const_all = all_scalar + bias0
        cst[16 + t] = ds + bias[16 + t];  // const_diag = diag_scalar + bias1
    }
}

__global__ __launch_bounds__(256) void kB(
    const float* __restrict__ vals, const int* __restrict__ row,
    const int* __restrict__ col, const float* __restrict__ W,
    const float* __restrict__ row_b, const float* __restrict__ col_b,
    const float* __restrict__ diag_b, const float* __restrict__ cst,
    float* __restrict__ out, int nnz)
{
    __shared__ float w0[256];
    __shared__ float scst[32];
    w0[threadIdx.x] = W[threadIdx.x];
    if (threadIdx.x < 32) scst[threadIdx.x] = cst[threadIdx.x];
    __syncthreads();

    int e = blockIdx.x * blockDim.x + threadIdx.x;
    if (e >= nnz) return;

    const float4* vp = (const float4*)(vals + (size_t)e * DF);
    float4 q0 = vp[0], q1 = vp[1], q2 = vp[2], q3 = vp[3];
    float v[16] = {q0.x, q0.y, q0.z, q0.w, q1.x, q1.y, q1.z, q1.w,
                   q2.x, q2.y, q2.z, q2.w, q3.x, q3.y, q3.z, q3.w};
    int r = row[e], c = col[e];

    float acc[16];
    const float4* rb = (const float4*)(row_b + (size_t)r * DF);
    const float4* cb = (const float4*)(col_b + (size_t)c * DF);
    #pragma unroll
    for (int k = 0; k < 4; ++k) {
        float4 a = rb[k], b = cb[k];
        acc[4 * k + 0] = scst[4 * k + 0] + a.x + b.x;
        acc[4 * k + 1] = scst[4 * k + 1] + a.y + b.y;
        acc[4 * k + 2] = scst[4 * k + 2] + a.z + b.z;
        acc[4 * k + 3] = scst[4 * k + 3] + a.w + b.w;
    }
    if (r == c) {
        const float4* db = (const float4*)(diag_b + (size_t)r * DF);
        #pragma unroll
        for (int k = 0; k < 4; ++k) {
            float4 d = db[k];
            acc[4 * k + 0] += d.x + scst[16 + 4 * k + 0];
            acc[4 * k + 1] += d.y + scst[16 + 4 * k + 1];
            acc[4 * k + 2] += d.z + scst[16 + 4 * k + 2];
            acc[4 * k + 3] += d.w + scst[16 + 4 * k + 3];
        }
    }
    #pragma unroll
    for (int i = 0; i < 16; ++i) {
        float vi = v[i];
        #pragma unroll
        for (int j = 0; j < 16; ++j) acc[j] = fmaf(vi, w0[i * 16 + j], acc[j]);
    }
    float4* op = (float4*)(out + (size_t)e * DF);
    op[0] = make_float4(acc[0], acc[1], acc[2], acc[3]);
    op[1] = make_float4(acc[4], acc[5], acc[6], acc[7]);
    op[2] = make_float4(acc[8], acc[9], acc[10], acc[11]);
    op[3] = make_float4(acc[12], acc[13], acc[14], acc[15]);
}

// 16 lanes per transpose-entry: lane j computes feature j and the 16 atomics
// of one entry land contiguously on one 64B line in a single instruction.
__global__ __launch_bounds__(256) void kC(
    const float* __restrict__ vals, const int* __restrict__ tin,
    const int* __restrict__ tout, const float* __restrict__ W,
    float* __restrict__ out, int nnzt)
{
    __shared__ float w1[256];
    for (int i = threadIdx.x; i < 256; i += blockDim.x) w1[i] = W[256 + i];
    __syncthreads();

    int gid = blockIdx.x * blockDim.x + threadIdx.x;
    int t = gid >> 4;   // transpose-entry index
    int j = gid & 15;   // feature index
    if (t >= nnzt) return;
    int ei = tin[t], eo = tout[t];

    float vj = vals[(size_t)ei * DF + j];  // 16 lanes -> one 64B line
    float acc = 0.f;
    #pragma unroll
    for (int i = 0; i < 16; ++i) {
        float vi = __shfl(vj, i, 16);      // broadcast v_i within 16-lane group
        acc = fmaf(vi, w1[i * 16 + j], acc);
    }
    atomicAdd(&out[(size_t)eo * DF + j], acc);
}

extern "C" void kernel_launch(void* const* d_in, const int* in_sizes, int n_in,
                              void* d_out, int out_size, void* d_ws, size_t ws_size,
                              hipStream_t stream)
{
    const float* vals    = (const float*)d_in[0];
    const float* weights = (const float*)d_in[1];
    const float* bias    = (const float*)d_in[2];
    const int*   row     = (const int*)d_in[3];
    const int*   col     = (const int*)d_in[4];
    const int*   tin     = (const int*)d_in[5];
    const int*   tout    = (const int*)d_in[6];

    const int nnz  = in_sizes[0] / DF;
    const int nnzt = in_sizes[5];
    const int n    = NNODES;
    const int nblkn = (n + 255) / 256;

    float* ws = (float*)d_ws;
    float* sum_row = ws;
    float* sum_col = sum_row + (size_t)n * DF;
    float* Dsum    = sum_col + (size_t)n * DF;
    float* cnt_row = Dsum + (size_t)n * DF;
    float* cnt_col = cnt_row + n;
    float* row_b   = cnt_col + n;
    float* col_b   = row_b + (size_t)n * DF;
    float* diag_b  = col_b + (size_t)n * DF;
    float* pa_part = diag_b + (size_t)n * DF;
    float* pd_part = pa_part + (size_t)NBLKA * DF;
    float* cst     = pd_part + (size_t)nblkn * DF;

    // zero the atomic-accumulation region: sum_row..cnt_col == n*50 floats
    hipMemsetAsync(ws, 0, (size_t)n * 50 * sizeof(float), stream);

    kA<<<NBLKA, 256, 0, stream>>>(vals, row, col, nnz, sum_row, sum_col, Dsum,
                                  cnt_row, cnt_col, pa_part);
    kN<<<nblkn, 256, 0, stream>>>(weights, sum_row, sum_col, Dsum, cnt_row,
                                  cnt_col, row_b, col_b, diag_b, pd_part, n);
    kS<<<1, 256, 0, stream>>>(weights, bias, pa_part, NBLKA, pd_part, nblkn,
                              1.f / (float)nnz, 1.f / (float)n, cst);
    kB<<<(nnz + 255) / 256, 256, 0, stream>>>(vals, row, col, weights, row_b,
                                              col_b, diag_b, cst, (float*)d_out, nnz);

    long long tthreads = (long long)nnzt * DF;
    kC<<<(int)((tthreads + 255) / 256), 256, 0, stream>>>(vals, tin, tout, weights,
                                                          (float*)d_out, nnzt);
}